// Round 2
// baseline (236.275 us; speedup 1.0000x reference)
//
#include <hip/hip_runtime.h>

typedef _Float16 f16;
typedef _Float16 f16x8 __attribute__((ext_vector_type(8)));
typedef _Float16 f16x4 __attribute__((ext_vector_type(4)));
typedef float    f32x4 __attribute__((ext_vector_type(4)));

__device__ __forceinline__ float sigmf(float x) {
    return __builtin_amdgcn_rcpf(1.0f + __expf(-x));
}
__device__ __forceinline__ float tanhf_fast(float x) {
    return 2.0f * sigmf(2.0f * x) - 1.0f;   // saturates correctly for large |x|
}

// LDS geometry (f16 elems)
constexpr int WG_SZ = 9 * 2048;    // gates W^T: [9 kb][256 n][8]  (kb0-7: W_hh, kb8: W_ih j<5)
constexpr int W1_SZ = 8 * 2048;    // W1^T: [8][256][8]
constexpr int W2_SZ = 32 * 512;    // W2^T: [32][64][8]
constexpr int W3_SZ = 8 * 256;     // W3^T: [8][32][8]
constexpr int W4_SZ = 4 * 128;     // W4^T: [4][16][8]
constexpr int WH_SZ = 2 * 128;     // Wh^T: [2][16][8] (K=16 real, rest via zero slab)
constexpr int KBS   = 2064;        // ABUF kb-slab stride: 256 rows*8 + 16 pad (+8 banks/kb)
constexpr int AB_SZ = 9 * KBS;     // kb0-7: h/z activations (K=64), kb8: x
constexpr int Z_SZ  = 2064;        // shared zero slab (A-side rows and B-side n both fit)

__global__ __launch_bounds__(1024, 1)
void lstmdqn_fused(const float* __restrict__ xg,  const float* __restrict__ h0g,
                   const float* __restrict__ c0g,
                   const float* __restrict__ Wih, const float* __restrict__ Whh,
                   const float* __restrict__ bih, const float* __restrict__ bhh,
                   const float* __restrict__ w1p, const float* __restrict__ b1p,
                   const float* __restrict__ w2p, const float* __restrict__ b2p,
                   const float* __restrict__ w3p, const float* __restrict__ b3p,
                   const float* __restrict__ w4p, const float* __restrict__ b4p,
                   const float* __restrict__ whp, const float* __restrict__ bhp,
                   float* __restrict__ out, int Bsz, int ntiles) {
    __shared__ f16 sWG[WG_SZ];
    __shared__ f16 sW1[W1_SZ];
    __shared__ f16 sW2[W2_SZ];
    __shared__ f16 sW3[W3_SZ];
    __shared__ f16 sW4[W4_SZ];
    __shared__ f16 sWHf[WH_SZ];
    __shared__ f16 sAB[AB_SZ];
    __shared__ f16 sZERO[Z_SZ];
    __shared__ float sBG[256], sB1[256], sB2[64], sB3[32], sB4[16], sBH[4];

    const int tid  = threadIdx.x;
    const int w    = tid >> 6;     // wave 0..15
    const int l    = tid & 63;
    const int lrow = l & 15;       // A row / B col / D col within tile
    const int lk   = l >> 4;       // k-chunk selector (0..3)
    const int wrow = w * 16;       // this wave's row base in LDS buffers

    // ---------------- weight staging (once per block) ----------------
    for (int idx = tid; idx < WG_SZ; idx += 1024) {
        int kb = idx >> 11, n = (idx >> 3) & 255, j = idx & 7;
        float v;
        if (kb < 8) v = Whh[n * 64 + kb * 8 + j];
        else        v = (j < 5) ? Wih[n * 5 + j] : 0.0f;
        sWG[idx] = (f16)v;
    }
    for (int idx = tid; idx < W1_SZ; idx += 1024) {
        int kb = idx >> 11, n = (idx >> 3) & 255, j = idx & 7;
        sW1[idx] = (f16)w1p[n * 64 + kb * 8 + j];
    }
    for (int idx = tid; idx < W2_SZ; idx += 1024) {
        int kb = idx >> 9, n = (idx >> 3) & 63, j = idx & 7;
        sW2[idx] = (f16)w2p[n * 256 + kb * 8 + j];
    }
    for (int idx = tid; idx < W3_SZ; idx += 1024) {
        int kb = idx >> 8, n = (idx >> 3) & 31, j = idx & 7;
        sW3[idx] = (f16)w3p[n * 64 + kb * 8 + j];
    }
    for (int idx = tid; idx < W4_SZ; idx += 1024) {
        int kb = idx >> 7, n = (idx >> 3) & 15, j = idx & 7;
        sW4[idx] = (f16)w4p[n * 32 + kb * 8 + j];
    }
    if (tid < WH_SZ) {  // head B fragments: B[k][col=n] = Wh[n][k], n>=3 -> 0
        int kb = tid >> 7, n = (tid >> 3) & 15, j = tid & 7;
        int k = kb * 8 + j;
        sWHf[tid] = (f16)((n < 3) ? whp[n * 16 + k] : 0.0f);
    }
    for (int idx = tid; idx < Z_SZ; idx += 1024) sZERO[idx] = (f16)0.0f;
    // zero x-slab (kb8) once: j>=5 stays zero forever; j<5 overwritten per step per wave
    for (int idx = tid; idx < KBS; idx += 1024) sAB[8 * KBS + idx] = (f16)0.0f;
    if (tid < 256) { sBG[tid] = bih[tid] + bhh[tid]; sB1[tid] = b1p[tid]; }
    if (tid < 64)  sB2[tid] = b2p[tid];
    if (tid < 32)  sB3[tid] = b3p[tid];
    if (tid < 16)  sB4[tid] = b4p[tid];
    if (tid < 3)   sBH[tid] = bhp[tid];
    __syncthreads();
    // ---- from here on: every wave touches only its own 16 LDS rows -> no barriers ----

    // per-lane bases for the zero-padded third gate k-tile and head k-tile
    const f16* a2base = (lk == 0) ? &sAB[8 * KBS] : sZERO;  // + (wrow+lrow)*8
    const f16* b2base = (lk == 0) ? &sWG[8 * 2048] : sZERO; // + n*8
    const f16* aHbase = (lk < 2) ? &sAB[lk * KBS] : sZERO;  // + (wrow+lrow)*8
    const f16* bHbase = (lk < 2) ? &sWHf[lk * 128] : sZERO; // + lrow*8

    #pragma unroll 1
    for (int tile = blockIdx.x * 16 + w; tile < ntiles; tile += gridDim.x * 16) {
        const int rbase = tile * 16;

        // stage h0 -> ABUF kb0..7 (f16): wave covers its 16x64 block, float4 loads
        {
            const float* hp = h0g + (size_t)rbase * 64;
            #pragma unroll
            for (int e = 0; e < 4; ++e) {
                float4 v = *(const float4*)(hp + e * 256 + l * 4);
                int r  = wrow + 4 * e + (l >> 4);
                int kb = (l >> 1) & 7;
                int j  = 4 * (l & 1);
                f16x4 h4 = { (f16)v.x, (f16)v.y, (f16)v.z, (f16)v.w };
                *reinterpret_cast<f16x4*>(&sAB[kb * KBS + r * 8 + j]) = h4;
            }
        }
        // c0 -> registers in D-fragment layout: creg[ct][q] = c[4*lk+q][ct*16+lrow]
        float creg[4][4];
        #pragma unroll
        for (int ct = 0; ct < 4; ++ct)
            #pragma unroll
            for (int q = 0; q < 4; ++q)
                creg[ct][q] = c0g[(size_t)(rbase + 4 * lk + q) * 64 + ct * 16 + lrow];

        // ---------------- 2 LSTM steps ----------------
        #pragma unroll
        for (int t = 0; t < 2; ++t) {
            // stage x_t (5 features) into ABUF kb8 j<5, own rows
            {
                const float* xp = xg + (size_t)t * Bsz * 5 + (size_t)rbase * 5;
                int r = l / 5, j = l - 5 * r;
                if (l < 64) sAB[8 * KBS + (wrow + r) * 8 + j] = (f16)xp[l];
                if (l < 16) {
                    int idx = 64 + l; int r2 = idx / 5, j2 = idx - 5 * r2;
                    sAB[8 * KBS + (wrow + r2) * 8 + j2] = (f16)xp[idx];
                }
            }
            // A fragments (K=96 -> 3 k-tiles; 3rd is x padded via zero slab)
            f16x8 af0 = *reinterpret_cast<const f16x8*>(&sAB[(0 + lk) * KBS + (wrow + lrow) * 8]);
            f16x8 af1 = *reinterpret_cast<const f16x8*>(&sAB[(4 + lk) * KBS + (wrow + lrow) * 8]);
            f16x8 af2 = *reinterpret_cast<const f16x8*>(&a2base[(wrow + lrow) * 8]);

            f32x4 acc[16];
            #pragma unroll
            for (int ct = 0; ct < 16; ++ct) {
                int n = ct * 16 + lrow;
                float bv = sBG[n];
                f32x4 a = { bv, bv, bv, bv };
                a = __builtin_amdgcn_mfma_f32_16x16x32_f16(af0,
                        *reinterpret_cast<const f16x8*>(&sWG[(0 + lk) * 2048 + n * 8]), a, 0, 0, 0);
                a = __builtin_amdgcn_mfma_f32_16x16x32_f16(af1,
                        *reinterpret_cast<const f16x8*>(&sWG[(4 + lk) * 2048 + n * 8]), a, 0, 0, 0);
                a = __builtin_amdgcn_mfma_f32_16x16x32_f16(af2,
                        *reinterpret_cast<const f16x8*>(&b2base[n * 8]), a, 0, 0, 0);
                acc[ct] = a;
            }
            // elementwise LSTM cell (gate order i,f,g,o along cols): fully in-register
            #pragma unroll
            for (int ct = 0; ct < 4; ++ct) {
                #pragma unroll
                for (int q = 0; q < 4; ++q) {
                    float iv = sigmf(acc[ct][q]);
                    float fv = sigmf(acc[4 + ct][q]);
                    float gv = tanhf_fast(acc[8 + ct][q]);
                    float ov = sigmf(acc[12 + ct][q]);
                    float c  = fv * creg[ct][q] + iv * gv;
                    creg[ct][q] = c;
                    float h = ov * tanhf_fast(c);
                    if (t == 1) h = fmaxf(h, 0.0f);      // z0 = relu(h2)
                    int n = ct * 16 + lrow;
                    sAB[(n >> 3) * KBS + (wrow + 4 * lk + q) * 8 + (n & 7)] = (f16)h;
                }
            }
        }

        // ---------------- z1 = relu(z0 @ W1^T + b1), [16,256], K=64 ----------------
        {
            f16x8 a0 = *reinterpret_cast<const f16x8*>(&sAB[(0 + lk) * KBS + (wrow + lrow) * 8]);
            f16x8 a1 = *reinterpret_cast<const f16x8*>(&sAB[(4 + lk) * KBS + (wrow + lrow) * 8]);
            f32x4 acc1[16];
            #pragma unroll
            for (int ct = 0; ct < 16; ++ct) {
                int n = ct * 16 + lrow;
                float bv = sB1[n];
                f32x4 a = { bv, bv, bv, bv };
                a = __builtin_amdgcn_mfma_f32_16x16x32_f16(a0,
                        *reinterpret_cast<const f16x8*>(&sW1[(0 + lk) * 2048 + n * 8]), a, 0, 0, 0);
                a = __builtin_amdgcn_mfma_f32_16x16x32_f16(a1,
                        *reinterpret_cast<const f16x8*>(&sW1[(4 + lk) * 2048 + n * 8]), a, 0, 0, 0);
                acc1[ct] = a;
            }
            // ------------ z2 = relu(z1 @ W2^T + b2), [16,64], K=256 in 4 chunks ------------
            f32x4 acc2[4];
            #pragma unroll
            for (int ct2 = 0; ct2 < 4; ++ct2) {
                float bv = sB2[ct2 * 16 + lrow];
                acc2[ct2] = (f32x4){ bv, bv, bv, bv };
            }
            #pragma unroll
            for (int cc = 0; cc < 4; ++cc) {
                #pragma unroll
                for (int ctl = 0; ctl < 4; ++ctl)
                    #pragma unroll
                    for (int q = 0; q < 4; ++q) {
                        float v = fmaxf(acc1[cc * 4 + ctl][q], 0.0f);
                        int n = ctl * 16 + lrow;
                        sAB[(n >> 3) * KBS + (wrow + 4 * lk + q) * 8 + (n & 7)] = (f16)v;
                    }
                f16x8 b0 = *reinterpret_cast<const f16x8*>(&sAB[(0 + lk) * KBS + (wrow + lrow) * 8]);
                f16x8 b1 = *reinterpret_cast<const f16x8*>(&sAB[(4 + lk) * KBS + (wrow + lrow) * 8]);
                #pragma unroll
                for (int ct2 = 0; ct2 < 4; ++ct2) {
                    acc2[ct2] = __builtin_amdgcn_mfma_f32_16x16x32_f16(b0,
                        *reinterpret_cast<const f16x8*>(&sW2[(cc * 8 + 0 + lk) * 512 + (ct2 * 16 + lrow) * 8]), acc2[ct2], 0, 0, 0);
                    acc2[ct2] = __builtin_amdgcn_mfma_f32_16x16x32_f16(b1,
                        *reinterpret_cast<const f16x8*>(&sW2[(cc * 8 + 4 + lk) * 512 + (ct2 * 16 + lrow) * 8]), acc2[ct2], 0, 0, 0);
                }
            }
            // ------------ z3 = relu(z2 @ W3^T + b3), [16,32], K=64 ------------
            #pragma unroll
            for (int ct2 = 0; ct2 < 4; ++ct2)
                #pragma unroll
                for (int q = 0; q < 4; ++q) {
                    float v = fmaxf(acc2[ct2][q], 0.0f);
                    int n = ct2 * 16 + lrow;
                    sAB[(n >> 3) * KBS + (wrow + 4 * lk + q) * 8 + (n & 7)] = (f16)v;
                }
            f16x8 a30 = *reinterpret_cast<const f16x8*>(&sAB[(0 + lk) * KBS + (wrow + lrow) * 8]);
            f16x8 a31 = *reinterpret_cast<const f16x8*>(&sAB[(4 + lk) * KBS + (wrow + lrow) * 8]);
            f32x4 acc3[2];
            #pragma unroll
            for (int ct3 = 0; ct3 < 2; ++ct3) {
                int n = ct3 * 16 + lrow;
                float bv = sB3[n];
                f32x4 a = { bv, bv, bv, bv };
                a = __builtin_amdgcn_mfma_f32_16x16x32_f16(a30,
                        *reinterpret_cast<const f16x8*>(&sW3[(0 + lk) * 256 + n * 8]), a, 0, 0, 0);
                a = __builtin_amdgcn_mfma_f32_16x16x32_f16(a31,
                        *reinterpret_cast<const f16x8*>(&sW3[(4 + lk) * 256 + n * 8]), a, 0, 0, 0);
                acc3[ct3] = a;
            }
            // ------------ z4 = relu(z3 @ W4^T + b4), [16,16], K=32 ------------
            #pragma unroll
            for (int ct3 = 0; ct3 < 2; ++ct3)
                #pragma unroll
                for (int q = 0; q < 4; ++q) {
                    float v = fmaxf(acc3[ct3][q], 0.0f);
                    int n = ct3 * 16 + lrow;               // 0..31 -> kb 0..3
                    sAB[(n >> 3) * KBS + (wrow + 4 * lk + q) * 8 + (n & 7)] = (f16)v;
                }
            f16x8 a4 = *reinterpret_cast<const f16x8*>(&sAB[lk * KBS + (wrow + lrow) * 8]);
            float bv4 = sB4[lrow];
            f32x4 acc4 = { bv4, bv4, bv4, bv4 };
            acc4 = __builtin_amdgcn_mfma_f32_16x16x32_f16(a4,
                        *reinterpret_cast<const f16x8*>(&sW4[lk * 128 + lrow * 8]), acc4, 0, 0, 0);
            // ------------ head: out = relu(z4) @ Wh^T + bh via one MFMA (K=16 padded) ------------
            #pragma unroll
            for (int q = 0; q < 4; ++q) {
                float v = fmaxf(acc4[q], 0.0f);
                sAB[(lrow >> 3) * KBS + (wrow + 4 * lk + q) * 8 + (lrow & 7)] = (f16)v;
            }
            f16x8 aH = *reinterpret_cast<const f16x8*>(&aHbase[(wrow + lrow) * 8]);
            float bvh = (lrow < 3) ? sBH[lrow] : 0.0f;
            f32x4 accH = { bvh, bvh, bvh, bvh };
            accH = __builtin_amdgcn_mfma_f32_16x16x32_f16(aH,
                        *reinterpret_cast<const f16x8*>(&bHbase[lrow * 8]), accH, 0, 0, 0);
            if (lrow < 3) {
                #pragma unroll
                for (int q = 0; q < 4; ++q)
                    out[(size_t)(rbase + 4 * lk + q) * 3 + lrow] = accH[q];
            }
        }
    }
}

extern "C" void kernel_launch(void* const* d_in, const int* in_sizes, int n_in,
                              void* d_out, int out_size, void* d_ws, size_t ws_size,
                              hipStream_t stream) {
    const float* x   = (const float*)d_in[0];
    const float* h0  = (const float*)d_in[1];
    const float* c0  = (const float*)d_in[2];
    const float* Wih = (const float*)d_in[3];
    const float* Whh = (const float*)d_in[4];
    const float* bih = (const float*)d_in[5];
    const float* bhh = (const float*)d_in[6];
    const float* w1  = (const float*)d_in[7];
    const float* b1  = (const float*)d_in[8];
    const float* w2  = (const float*)d_in[9];
    const float* b2  = (const float*)d_in[10];
    const float* w3  = (const float*)d_in[11];
    const float* b3  = (const float*)d_in[12];
    const float* w4  = (const float*)d_in[13];
    const float* b4  = (const float*)d_in[14];
    const float* wh  = (const float*)d_in[15];
    const float* bh  = (const float*)d_in[16];

    int Bsz    = in_sizes[1] / 64;   // h0 is [B, 64]
    int ntiles = Bsz / 16;
    int grid   = 256;                // 1 block/CU, 16 wave-tiles per block, 4 persistent iters

    lstmdqn_fused<<<grid, 1024, 0, stream>>>(x, h0, c0, Wih, Whh, bih, bhh,
                                             w1, b1, w2, b2, w3, b3, w4, b4, wh, bh,
                                             (float*)d_out, Bsz, ntiles);
}

// Round 3
// 125.629 us; speedup vs baseline: 1.8807x; 1.8807x over previous
//
#include <hip/hip_runtime.h>

typedef _Float16 f16;
typedef _Float16 f16x8 __attribute__((ext_vector_type(8)));
typedef _Float16 f16x4 __attribute__((ext_vector_type(4)));
typedef float    f32x4 __attribute__((ext_vector_type(4)));

__device__ __forceinline__ float sigmf(float x) {
    return __builtin_amdgcn_rcpf(1.0f + __expf(-x));
}
__device__ __forceinline__ float tanhf_fast(float x) {
    return 2.0f * sigmf(2.0f * x) - 1.0f;   // saturates correctly for large |x|
}

// LDS geometry (f16 elems)
constexpr int WG_SZ = 9 * 2048;    // gates W^T: [9 kb][256 n][8]  (kb0-7: W_hh, kb8: W_ih j<5)
constexpr int W1_SZ = 8 * 2048;    // W1^T: [8][256][8]
constexpr int W2_SZ = 32 * 512;    // W2^T: [32][64][8]
constexpr int W3_SZ = 8 * 256;     // W3^T: [8][32][8]
constexpr int W4_SZ = 4 * 128;     // W4^T: [4][16][8]
constexpr int WH_SZ = 2 * 128;     // Wh^T: [2][16][8] (K=16 real, rest via zero slab)
constexpr int KBS   = 2064;        // ABUF kb-slab stride: 256 rows*8 + 16 pad (+8 banks/kb)
constexpr int AB_SZ = 9 * KBS;     // kb0-7: h/z activations (K=64), kb8: x
constexpr int Z_SZ  = 2064;        // shared zero slab (covers 256 rows * 8)

__global__ __launch_bounds__(512, 2)
void lstmdqn_fused(const float* __restrict__ xg,  const float* __restrict__ h0g,
                   const float* __restrict__ c0g,
                   const float* __restrict__ Wih, const float* __restrict__ Whh,
                   const float* __restrict__ bih, const float* __restrict__ bhh,
                   const float* __restrict__ w1p, const float* __restrict__ b1p,
                   const float* __restrict__ w2p, const float* __restrict__ b2p,
                   const float* __restrict__ w3p, const float* __restrict__ b3p,
                   const float* __restrict__ w4p, const float* __restrict__ b4p,
                   const float* __restrict__ whp, const float* __restrict__ bhp,
                   float* __restrict__ out, int Bsz, int ntiles) {
    __shared__ f16 sWG[WG_SZ];
    __shared__ f16 sW1[W1_SZ];
    __shared__ f16 sW2[W2_SZ];
    __shared__ f16 sW3[W3_SZ];
    __shared__ f16 sW4[W4_SZ];
    __shared__ f16 sWHf[WH_SZ];
    __shared__ f16 sAB[AB_SZ];
    __shared__ f16 sZERO[Z_SZ];
    __shared__ float sBG[256], sB1[256], sB2[64], sB3[32], sB4[16], sBH[4];

    const int tid  = threadIdx.x;
    const int w    = tid >> 6;     // wave 0..7
    const int l    = tid & 63;
    const int lrow = l & 15;       // A row / B col / D col within tile
    const int lk   = l >> 4;       // k-chunk selector (0..3)

    // ---------------- weight staging (once per block) ----------------
    for (int idx = tid; idx < WG_SZ; idx += 512) {
        int kb = idx >> 11, n = (idx >> 3) & 255, j = idx & 7;
        float v;
        if (kb < 8) v = Whh[n * 64 + kb * 8 + j];
        else        v = (j < 5) ? Wih[n * 5 + j] : 0.0f;
        sWG[idx] = (f16)v;
    }
    for (int idx = tid; idx < W1_SZ; idx += 512) {
        int kb = idx >> 11, n = (idx >> 3) & 255, j = idx & 7;
        sW1[idx] = (f16)w1p[n * 64 + kb * 8 + j];
    }
    for (int idx = tid; idx < W2_SZ; idx += 512) {
        int kb = idx >> 9, n = (idx >> 3) & 63, j = idx & 7;
        sW2[idx] = (f16)w2p[n * 256 + kb * 8 + j];
    }
    for (int idx = tid; idx < W3_SZ; idx += 512) {
        int kb = idx >> 8, n = (idx >> 3) & 31, j = idx & 7;
        sW3[idx] = (f16)w3p[n * 64 + kb * 8 + j];
    }
    for (int idx = tid; idx < W4_SZ; idx += 512) {
        int kb = idx >> 7, n = (idx >> 3) & 15, j = idx & 7;
        sW4[idx] = (f16)w4p[n * 32 + kb * 8 + j];
    }
    if (tid < WH_SZ) {  // head B fragments: B[k][col=n] = Wh[n][k], n>=3 -> 0
        int kb = tid >> 7, n = (tid >> 3) & 15, j = tid & 7;
        int k = kb * 8 + j;
        sWHf[tid] = (f16)((n < 3) ? whp[n * 16 + k] : 0.0f);
    }
    for (int idx = tid; idx < Z_SZ; idx += 512) sZERO[idx] = (f16)0.0f;
    // zero x-slab (kb8) once: j>=5 stays zero forever; j<5 overwritten per step per wave
    for (int idx = tid; idx < KBS; idx += 512) sAB[8 * KBS + idx] = (f16)0.0f;
    if (tid < 256) { sBG[tid] = bih[tid] + bhh[tid]; sB1[tid] = b1p[tid]; }
    if (tid < 64)  sB2[tid] = b2p[tid];
    if (tid < 32)  sB3[tid] = b3p[tid];
    if (tid < 16)  sB4[tid] = b4p[tid];
    if (tid < 3)   sBH[tid] = bhp[tid];
    __syncthreads();
    // ---- from here on: every wave touches only its own 2x16 LDS rows -> no barriers ----

    // per-lane bases for zero-padded third gate k-tile and head k-tile
    const f16* a2base = (lk == 0) ? &sAB[8 * KBS] : sZERO;  // + row*8
    const f16* b2base = (lk == 0) ? &sWG[8 * 2048] : sZERO; // + n*8
    const f16* aHbase = (lk < 2) ? &sAB[lk * KBS] : sZERO;  // + row*8
    const f16* bHbase = (lk < 2) ? &sWHf[lk * 128] : sZERO; // + lrow*8

    #pragma unroll 1
    for (int tbase = blockIdx.x * 16; tbase < ntiles; tbase += gridDim.x * 16) {
        // this wave's two tiles: tbase+w (rows w*16..) and tbase+8+w (rows 128+w*16..)
        int   tile_[2]  = { tbase + w, tbase + 8 + w };
        int   wrow_[2]  = { w * 16, 128 + w * 16 };

        // stage h0 -> ABUF kb0..7 (f16): each tile's 16x64 block via float4 loads
        #pragma unroll
        for (int u = 0; u < 2; ++u) {
            const float* hp = h0g + (size_t)tile_[u] * 16 * 64;
            #pragma unroll
            for (int e = 0; e < 4; ++e) {
                float4 v = *(const float4*)(hp + e * 256 + l * 4);
                int r  = wrow_[u] + 4 * e + (l >> 4);
                int kb = (l >> 1) & 7;
                int j  = 4 * (l & 1);
                f16x4 h4 = { (f16)v.x, (f16)v.y, (f16)v.z, (f16)v.w };
                *reinterpret_cast<f16x4*>(&sAB[kb * KBS + r * 8 + j]) = h4;
            }
        }
        // c0 -> registers in D-fragment layout: creg[u][ct][q] = c[4*lk+q][ct*16+lrow]
        float creg[2][4][4];
        #pragma unroll
        for (int u = 0; u < 2; ++u)
            #pragma unroll
            for (int ct = 0; ct < 4; ++ct)
                #pragma unroll
                for (int q = 0; q < 4; ++q)
                    creg[u][ct][q] = c0g[(size_t)(tile_[u] * 16 + 4 * lk + q) * 64 + ct * 16 + lrow];

        // ---------------- 2 LSTM steps ----------------
        #pragma unroll
        for (int t = 0; t < 2; ++t) {
            // stage x_t (5 features) into ABUF kb8 j<5, own rows
            #pragma unroll
            for (int u = 0; u < 2; ++u) {
                const float* xp = xg + (size_t)t * Bsz * 5 + (size_t)tile_[u] * 16 * 5;
                int r = l / 5, j = l - 5 * r;
                if (l < 64) sAB[8 * KBS + (wrow_[u] + r) * 8 + j] = (f16)xp[l];
                if (l < 16) {
                    int idx = 64 + l; int r2 = idx / 5, j2 = idx - 5 * r2;
                    sAB[8 * KBS + (wrow_[u] + r2) * 8 + j2] = (f16)xp[idx];
                }
            }
            // A fragments (K=96 -> 3 k-tiles; 3rd is x padded via zero slab)
            f16x8 af0[2], af1[2], af2[2];
            #pragma unroll
            for (int u = 0; u < 2; ++u) {
                int row = wrow_[u] + lrow;
                af0[u] = *reinterpret_cast<const f16x8*>(&sAB[(0 + lk) * KBS + row * 8]);
                af1[u] = *reinterpret_cast<const f16x8*>(&sAB[(4 + lk) * KBS + row * 8]);
                af2[u] = *reinterpret_cast<const f16x8*>(&a2base[row * 8]);
            }

            f32x4 acc[2][16];
            #pragma unroll
            for (int ct = 0; ct < 16; ++ct) {
                int n = ct * 16 + lrow;
                float bv = sBG[n];
                f16x8 bf0 = *reinterpret_cast<const f16x8*>(&sWG[(0 + lk) * 2048 + n * 8]);
                f16x8 bf1 = *reinterpret_cast<const f16x8*>(&sWG[(4 + lk) * 2048 + n * 8]);
                f16x8 bf2 = *reinterpret_cast<const f16x8*>(&b2base[n * 8]);
                #pragma unroll
                for (int u = 0; u < 2; ++u) {
                    f32x4 a = { bv, bv, bv, bv };
                    a = __builtin_amdgcn_mfma_f32_16x16x32_f16(af0[u], bf0, a, 0, 0, 0);
                    a = __builtin_amdgcn_mfma_f32_16x16x32_f16(af1[u], bf1, a, 0, 0, 0);
                    a = __builtin_amdgcn_mfma_f32_16x16x32_f16(af2[u], bf2, a, 0, 0, 0);
                    acc[u][ct] = a;
                }
            }
            // elementwise LSTM cell (gate order i,f,g,o along cols): fully in-register
            #pragma unroll
            for (int u = 0; u < 2; ++u)
                #pragma unroll
                for (int ct = 0; ct < 4; ++ct)
                    #pragma unroll
                    for (int q = 0; q < 4; ++q) {
                        float iv = sigmf(acc[u][ct][q]);
                        float fv = sigmf(acc[u][4 + ct][q]);
                        float gv = tanhf_fast(acc[u][8 + ct][q]);
                        float ov = sigmf(acc[u][12 + ct][q]);
                        float c  = fv * creg[u][ct][q] + iv * gv;
                        creg[u][ct][q] = c;
                        float h = ov * tanhf_fast(c);
                        if (t == 1) h = fmaxf(h, 0.0f);      // z0 = relu(h2)
                        int n = ct * 16 + lrow;
                        sAB[(n >> 3) * KBS + (wrow_[u] + 4 * lk + q) * 8 + (n & 7)] = (f16)h;
                    }
        }

        // ---------------- z1 = relu(z0 @ W1^T + b1), [16,256], K=64 ----------------
        {
            f16x8 a0[2], a1[2];
            #pragma unroll
            for (int u = 0; u < 2; ++u) {
                int row = wrow_[u] + lrow;
                a0[u] = *reinterpret_cast<const f16x8*>(&sAB[(0 + lk) * KBS + row * 8]);
                a1[u] = *reinterpret_cast<const f16x8*>(&sAB[(4 + lk) * KBS + row * 8]);
            }
            f32x4 acc1[2][16];
            #pragma unroll
            for (int ct = 0; ct < 16; ++ct) {
                int n = ct * 16 + lrow;
                float bv = sB1[n];
                f16x8 bf0 = *reinterpret_cast<const f16x8*>(&sW1[(0 + lk) * 2048 + n * 8]);
                f16x8 bf1 = *reinterpret_cast<const f16x8*>(&sW1[(4 + lk) * 2048 + n * 8]);
                #pragma unroll
                for (int u = 0; u < 2; ++u) {
                    f32x4 a = { bv, bv, bv, bv };
                    a = __builtin_amdgcn_mfma_f32_16x16x32_f16(a0[u], bf0, a, 0, 0, 0);
                    a = __builtin_amdgcn_mfma_f32_16x16x32_f16(a1[u], bf1, a, 0, 0, 0);
                    acc1[u][ct] = a;
                }
            }
            // ------------ z2 = relu(z1 @ W2^T + b2), [16,64], K=256 in 4 chunks ------------
            f32x4 acc2[2][4];
            #pragma unroll
            for (int u = 0; u < 2; ++u)
                #pragma unroll
                for (int ct2 = 0; ct2 < 4; ++ct2) {
                    float bv = sB2[ct2 * 16 + lrow];
                    acc2[u][ct2] = (f32x4){ bv, bv, bv, bv };
                }
            #pragma unroll
            for (int cc = 0; cc < 4; ++cc) {
                #pragma unroll
                for (int u = 0; u < 2; ++u)
                    #pragma unroll
                    for (int ctl = 0; ctl < 4; ++ctl)
                        #pragma unroll
                        for (int q = 0; q < 4; ++q) {
                            float v = fmaxf(acc1[u][cc * 4 + ctl][q], 0.0f);
                            int n = ctl * 16 + lrow;
                            sAB[(n >> 3) * KBS + (wrow_[u] + 4 * lk + q) * 8 + (n & 7)] = (f16)v;
                        }
                f16x8 b0[2], b1[2];
                #pragma unroll
                for (int u = 0; u < 2; ++u) {
                    int row = wrow_[u] + lrow;
                    b0[u] = *reinterpret_cast<const f16x8*>(&sAB[(0 + lk) * KBS + row * 8]);
                    b1[u] = *reinterpret_cast<const f16x8*>(&sAB[(4 + lk) * KBS + row * 8]);
                }
                #pragma unroll
                for (int ct2 = 0; ct2 < 4; ++ct2) {
                    f16x8 wf0 = *reinterpret_cast<const f16x8*>(&sW2[(cc * 8 + 0 + lk) * 512 + (ct2 * 16 + lrow) * 8]);
                    f16x8 wf1 = *reinterpret_cast<const f16x8*>(&sW2[(cc * 8 + 4 + lk) * 512 + (ct2 * 16 + lrow) * 8]);
                    #pragma unroll
                    for (int u = 0; u < 2; ++u) {
                        acc2[u][ct2] = __builtin_amdgcn_mfma_f32_16x16x32_f16(b0[u], wf0, acc2[u][ct2], 0, 0, 0);
                        acc2[u][ct2] = __builtin_amdgcn_mfma_f32_16x16x32_f16(b1[u], wf1, acc2[u][ct2], 0, 0, 0);
                    }
                }
            }
            // ------------ z3 = relu(z2 @ W3^T + b3), [16,32], K=64 ------------
            #pragma unroll
            for (int u = 0; u < 2; ++u)
                #pragma unroll
                for (int ct2 = 0; ct2 < 4; ++ct2)
                    #pragma unroll
                    for (int q = 0; q < 4; ++q) {
                        float v = fmaxf(acc2[u][ct2][q], 0.0f);
                        int n = ct2 * 16 + lrow;
                        sAB[(n >> 3) * KBS + (wrow_[u] + 4 * lk + q) * 8 + (n & 7)] = (f16)v;
                    }
            f16x8 a30[2], a31[2];
            #pragma unroll
            for (int u = 0; u < 2; ++u) {
                int row = wrow_[u] + lrow;
                a30[u] = *reinterpret_cast<const f16x8*>(&sAB[(0 + lk) * KBS + row * 8]);
                a31[u] = *reinterpret_cast<const f16x8*>(&sAB[(4 + lk) * KBS + row * 8]);
            }
            f32x4 acc3[2][2];
            #pragma unroll
            for (int ct3 = 0; ct3 < 2; ++ct3) {
                int n = ct3 * 16 + lrow;
                float bv = sB3[n];
                f16x8 wf0 = *reinterpret_cast<const f16x8*>(&sW3[(0 + lk) * 256 + n * 8]);
                f16x8 wf1 = *reinterpret_cast<const f16x8*>(&sW3[(4 + lk) * 256 + n * 8]);
                #pragma unroll
                for (int u = 0; u < 2; ++u) {
                    f32x4 a = { bv, bv, bv, bv };
                    a = __builtin_amdgcn_mfma_f32_16x16x32_f16(a30[u], wf0, a, 0, 0, 0);
                    a = __builtin_amdgcn_mfma_f32_16x16x32_f16(a31[u], wf1, a, 0, 0, 0);
                    acc3[u][ct3] = a;
                }
            }
            // ------------ z4 = relu(z3 @ W4^T + b4), [16,16], K=32 ------------
            #pragma unroll
            for (int u = 0; u < 2; ++u)
                #pragma unroll
                for (int ct3 = 0; ct3 < 2; ++ct3)
                    #pragma unroll
                    for (int q = 0; q < 4; ++q) {
                        float v = fmaxf(acc3[u][ct3][q], 0.0f);
                        int n = ct3 * 16 + lrow;               // 0..31 -> kb 0..3
                        sAB[(n >> 3) * KBS + (wrow_[u] + 4 * lk + q) * 8 + (n & 7)] = (f16)v;
                    }
            f32x4 acc4[2];
            {
                float bv4 = sB4[lrow];
                f16x8 wf = *reinterpret_cast<const f16x8*>(&sW4[lk * 128 + lrow * 8]);
                #pragma unroll
                for (int u = 0; u < 2; ++u) {
                    f16x8 a4 = *reinterpret_cast<const f16x8*>(&sAB[lk * KBS + (wrow_[u] + lrow) * 8]);
                    f32x4 a = { bv4, bv4, bv4, bv4 };
                    acc4[u] = __builtin_amdgcn_mfma_f32_16x16x32_f16(a4, wf, a, 0, 0, 0);
                }
            }
            // ------------ head: out = relu(z4) @ Wh^T + bh via one MFMA (K=16 padded) ------------
            #pragma unroll
            for (int u = 0; u < 2; ++u)
                #pragma unroll
                for (int q = 0; q < 4; ++q) {
                    float v = fmaxf(acc4[u][q], 0.0f);
                    sAB[(lrow >> 3) * KBS + (wrow_[u] + 4 * lk + q) * 8 + (lrow & 7)] = (f16)v;
                }
            {
                float bvh = (lrow < 3) ? sBH[lrow] : 0.0f;
                f16x8 bfh = *reinterpret_cast<const f16x8*>(&bHbase[lrow * 8]);
                #pragma unroll
                for (int u = 0; u < 2; ++u) {
                    f16x8 aH = *reinterpret_cast<const f16x8*>(&aHbase[(wrow_[u] + lrow) * 8]);
                    f32x4 accH = { bvh, bvh, bvh, bvh };
                    accH = __builtin_amdgcn_mfma_f32_16x16x32_f16(aH, bfh, accH, 0, 0, 0);
                    if (lrow < 3) {
                        #pragma unroll
                        for (int q = 0; q < 4; ++q)
                            out[(size_t)(tile_[u] * 16 + 4 * lk + q) * 3 + lrow] = accH[q];
                    }
                }
            }
        }
    }
}

extern "C" void kernel_launch(void* const* d_in, const int* in_sizes, int n_in,
                              void* d_out, int out_size, void* d_ws, size_t ws_size,
                              hipStream_t stream) {
    const float* x   = (const float*)d_in[0];
    const float* h0  = (const float*)d_in[1];
    const float* c0  = (const float*)d_in[2];
    const float* Wih = (const float*)d_in[3];
    const float* Whh = (const float*)d_in[4];
    const float* bih = (const float*)d_in[5];
    const float* bhh = (const float*)d_in[6];
    const float* w1  = (const float*)d_in[7];
    const float* b1  = (const float*)d_in[8];
    const float* w2  = (const float*)d_in[9];
    const float* b2  = (const float*)d_in[10];
    const float* w3  = (const float*)d_in[11];
    const float* b3  = (const float*)d_in[12];
    const float* w4  = (const float*)d_in[13];
    const float* b4  = (const float*)d_in[14];
    const float* wh  = (const float*)d_in[15];
    const float* bh  = (const float*)d_in[16];

    int Bsz    = in_sizes[1] / 64;   // h0 is [B, 64]
    int ntiles = Bsz / 16;
    int grid   = 256;                // 1 block/CU persistent; 8 waves x 2 tiles; 4 iters

    lstmdqn_fused<<<grid, 512, 0, stream>>>(x, h0, c0, Wih, Whh, bih, bhh,
                                            w1, b1, w2, b2, w3, b3, w4, b4, wh, bh,
                                            (float*)d_out, Bsz, ntiles);
}